// Round 7
// baseline (183.511 us; speedup 1.0000x reference)
//
#include <hip/hip_runtime.h>

// LMMD loss, round 7 = round 6 + (a) 32 KB LDS (Vsw/red aliased) -> 4 blocks/CU
//                               + (b) swizzled Thi layout -> conflict-free ds_read_b128.
// loss = (1/n_idx) * sum_{p<=q} f_pq * w_pq * K(p,q),  f=2 off-diag, 1 diag
//   v_i = s_vec[i] (i<B), v_{B+j} = -t_vec[j]
//   K = sum_t y^(2^t), y = exp(-relu(l2)/d4), d4 = largest denom
// Features: bf16 MFMA (hi-only; exact-match verified rounds 2-6).
// Weights: SS lookup (exact) / ST LDS gather (bf16) / TT precomputed bf16 tiles.
// Thi swizzle: within each 64-B chunk of row p, logical quad q (16 B) is stored
// at physical slot (q + (p>>1)) & 3.  GLD16 copies slots linearly; fragment
// reads use slot (quad + (R>>1)) & 3 so each 16-lane b128 phase covers all 8
// bank groups 2-way (free) instead of 2 groups 8-way.

#define B 4096
#define D 256
#define C 31
#define N2 8192
#define NTILE 64                       // 128-row tiles over 2B rows
#define NBLK (NTILE * (NTILE + 1) / 2) // 2080
#define NTT (32 * 33 / 2)              // 528 TT tile pairs

typedef __attribute__((ext_vector_type(8))) short bf16x8;
typedef __attribute__((ext_vector_type(4))) float f32x4;

struct WS {
  double acc_loss;
  int s_cnt[32];
  float t_cnt[32];
  int t_pres[32];
  float s_div[32], t_div[32];
  float inv_n_idx;
  float inv_d4;
  float sq[N2];
  int slab[N2];
  float sdv[N2];
  float Mpart[256 * 256];
  alignas(16) unsigned short Thi[(size_t)N2 * D];   // bf16 features (swizzled)
  alignas(16) unsigned short vhi[(size_t)N2 * 32];  // bf16 v rows (linear)
  alignas(16) float v[(size_t)N2 * 32];             // exact f32 v rows
  alignas(16) unsigned short wtt[(size_t)NTT * 16384];  // bf16 TT weight tiles
};

static __device__ __forceinline__ unsigned short f2bf(float f) {
  unsigned int u = __float_as_uint(f);
  return (unsigned short)((u + 0x7fffu + ((u >> 16) & 1u)) >> 16);  // RNE
}
static __device__ __forceinline__ float bf2f(unsigned short s) {
  return __uint_as_float(((unsigned int)s) << 16);
}

#define GLD16(gsrc, ldst)                                                     \
  __builtin_amdgcn_global_load_lds(                                           \
      (const __attribute__((address_space(1))) void*)(gsrc),                  \
      (__attribute__((address_space(3))) void*)(ldst), 16, 0, 0)

__global__ void k0_init(WS* __restrict__ ws) {
  int tid = threadIdx.x;  // 64
  if (tid == 0) ws->acc_loss = 0.0;
  if (tid < 32) {
    ws->s_cnt[tid] = 0;
    ws->t_cnt[tid] = 0.f;
    ws->t_pres[tid] = 0;
  }
}

__global__ void kA1_stats(const int* __restrict__ s_label,
                          const float* __restrict__ t_label,
                          WS* __restrict__ ws) {
  __shared__ int ls[32];
  __shared__ float lt[32];
  __shared__ int lpres[32];
  int tid = threadIdx.x, lane = tid & 63;  // 256, 16 blocks
  if (tid < 32) { ls[tid] = 0; lt[tid] = 0.f; lpres[tid] = 0; }
  __syncthreads();
  int row = blockIdx.x * 256 + tid;
  atomicAdd(&ls[s_label[row]], 1);
  const float* r = t_label + (size_t)row * C;
  float best = -1e30f;
  int barg = 0;
#pragma unroll
  for (int c = 0; c < C; ++c) {
    float x = r[c];
    if (x > best) { best = x; barg = c; }  // first-max == jnp.argmax
    float s = x;
#pragma unroll
    for (int off = 32; off; off >>= 1) s += __shfl_down(s, off, 64);
    if (lane == 0) atomicAdd(&lt[c], s);
  }
  lpres[barg] = 1;  // benign race
  __syncthreads();
  if (tid < 32) {
    if (ls[tid]) atomicAdd(&ws->s_cnt[tid], ls[tid]);
    atomicAdd(&ws->t_cnt[tid], lt[tid]);
    if (lpres[tid]) ws->t_pres[tid] = 1;
  }
}

__global__ void kA2_final(WS* __restrict__ ws) {
  int tid = threadIdx.x;  // 64
  int m = 0;
  if (tid < 32) {
    int cnt = ws->s_cnt[tid];
    m = (tid < C) && (cnt > 0) && (ws->t_pres[tid] != 0);
    ws->s_div[tid] = m ? 1.f / (float)cnt : 0.f;
    float t = ws->t_cnt[tid];
    float ta = (t == 0.f) ? 100.f : t;
    ws->t_div[tid] = m ? 1.f / ta : 0.f;
  }
  unsigned long long bal = __ballot(m);
  if (tid == 0) ws->inv_n_idx = 1.f / fmaxf((float)__popcll(bal), 1.f);
}

__global__ __launch_bounds__(256) void kB_prep(const float* __restrict__ src,
                                               const float* __restrict__ tgt,
                                               const int* __restrict__ s_label,
                                               const float* __restrict__ t_label,
                                               WS* __restrict__ ws) {
  int tid = threadIdx.x, w = tid >> 6, lane = tid & 63;
  int r0 = blockIdx.x * 32;
  __shared__ float rsq[32];
  __shared__ float colp[4][256];
  float ca0 = 0.f, ca1 = 0.f, ca2 = 0.f, ca3 = 0.f;
  // swizzled destination pieces for this lane (row-dependent part added per-row)
  int ck = lane >> 3, qd = (lane >> 1) & 3, hf = lane & 1;
#pragma unroll
  for (int i = 0; i < 8; ++i) {
    int rr = w * 8 + i;
    int p = r0 + rr;
    const float* rp = (p < B) ? src + (size_t)p * D : tgt + (size_t)(p - B) * D;
    float4 x = *(const float4*)(rp + lane * 4);
    ushort4 hv;
    hv.x = f2bf(x.x); hv.y = f2bf(x.y); hv.z = f2bf(x.z); hv.w = f2bf(x.w);
    int slot = (qd + (p >> 1)) & 3;  // quad rotation within the 64-B chunk
    *(ushort4*)(&ws->Thi[(size_t)p * D + ck * 32 + slot * 8 + hf * 4]) = hv;
    ca0 += x.x; ca1 += x.y; ca2 += x.z; ca3 += x.w;
    float s = x.x * x.x + x.y * x.y + x.z * x.z + x.w * x.w;
#pragma unroll
    for (int off = 32; off; off >>= 1) s += __shfl_down(s, off, 64);
    if (lane == 0) rsq[rr] = s;
  }
  colp[w][lane * 4 + 0] = ca0;
  colp[w][lane * 4 + 1] = ca1;
  colp[w][lane * 4 + 2] = ca2;
  colp[w][lane * 4 + 3] = ca3;
  __syncthreads();
  if (tid < 32) {
    int p = r0 + tid;
    ws->sq[p] = rsq[tid];
    if (p < B) {
      int lb = s_label[p];
      ws->slab[p] = lb;
      ws->sdv[p] = ws->s_div[lb];
    } else {
      ws->slab[p] = 0;
      ws->sdv[p] = 0.f;
    }
  }
  ws->Mpart[(size_t)blockIdx.x * 256 + tid] =
      colp[0][tid] + colp[1][tid] + colp[2][tid] + colp[3][tid];
  int vr = tid >> 3, cb = (tid & 7) * 4;
  int p = r0 + vr;
  float vals[4];
#pragma unroll
  for (int j = 0; j < 4; ++j) {
    int c = cb + j;
    float val = 0.f;
    if (c < C) {
      if (p < B)
        val = (s_label[p] == c) ? ws->s_div[c] : 0.f;
      else
        val = -t_label[(size_t)(p - B) * C + c] * ws->t_div[c];
    }
    vals[j] = val;
  }
  float4 vf; vf.x = vals[0]; vf.y = vals[1]; vf.z = vals[2]; vf.w = vals[3];
  *(float4*)(&ws->v[(size_t)p * 32 + cb]) = vf;
  ushort4 vh;
  vh.x = f2bf(vals[0]); vh.y = f2bf(vals[1]);
  vh.z = f2bf(vals[2]); vh.w = f2bf(vals[3]);
  *(ushort4*)(&ws->vhi[(size_t)p * 32 + cb]) = vh;
}

__global__ void kC_bw(WS* __restrict__ ws) {
  int tid = threadIdx.x;  // 256
  double s = 0.0;
  for (int p = tid; p < N2; p += 256) s += (double)ws->sq[p];
  double col = 0.0;
  for (int b = 0; b < 256; ++b) col += (double)ws->Mpart[(size_t)b * 256 + tid];
  double m2 = col * col;
#pragma unroll
  for (int off = 32; off; off >>= 1) {
    s += __shfl_down(s, off, 64);
    m2 += __shfl_down(m2, off, 64);
  }
  __shared__ double ps[4], pm[4];
  if ((tid & 63) == 0) { ps[tid >> 6] = s; pm[tid >> 6] = m2; }
  __syncthreads();
  if (tid == 0) {
    double S = ps[0] + ps[1] + ps[2] + ps[3];
    double M2 = pm[0] + pm[1] + pm[2] + pm[3];
    double n = (double)N2;
    double sum_l2 = 2.0 * n * S - 2.0 * M2;
    double bw = sum_l2 / (n * n - n);
    bw = fmax(bw, 1e-6) * 0.25;
    double dc4 = fmax(bw * 16.0, 1e-6);
    ws->inv_d4 = (float)(1.0 / dc4);
  }
}

// Precompute TT weight tiles (bf16, stored in C-fragment order). vhi is linear.
__global__ __launch_bounds__(256, 2) void kW_tt(WS* __restrict__ ws) {
  int tid = threadIdx.x, w = tid >> 6, lane = tid & 63;
  int lin = blockIdx.x;
  int tp = 0;
  while (32 * (tp + 1) - ((tp + 1) * tp) / 2 <= lin) ++tp;
  int tq = tp + (lin - (32 * tp - (tp * (tp - 1)) / 2));
  int p0 = B + tp * 128, q0 = B + tq * 128;

  __shared__ __align__(16) unsigned short Ash[128 * 32];
  __shared__ __align__(16) unsigned short Bsh[128 * 32];
  const int wr = (w >> 1) * 64, wc = (w & 1) * 64;
  const int mrow = lane & 15, quad = lane >> 4;
  f32x4 acc[4][4];
#pragma unroll
  for (int i = 0; i < 4; ++i)
#pragma unroll
    for (int j = 0; j < 4; ++j) acc[i][j] = (f32x4){0.f, 0.f, 0.f, 0.f};

  int rA = tid >> 2, cp8 = (tid & 3) * 8;
  unsigned short* ldsA = Ash + w * 512;
  unsigned short* ldsB = Bsh + w * 512;
  const unsigned short* gA = ws->vhi + (size_t)(p0 + rA) * 32 + cp8;
  const unsigned short* gB = ws->vhi + (size_t)(q0 + rA) * 32 + cp8;
  GLD16(gA, ldsA);
  GLD16(gA + (size_t)64 * 32, ldsA + 2048);
  GLD16(gB, ldsB);
  GLD16(gB + (size_t)64 * 32, ldsB + 2048);
  __syncthreads();
  {
    bf16x8 af[4], bfr[4];
#pragma unroll
    for (int ti = 0; ti < 4; ++ti)
      af[ti] = *(const bf16x8*)(Ash + (wr + ti * 16 + mrow) * 32 + quad * 8);
#pragma unroll
    for (int tj = 0; tj < 4; ++tj)
      bfr[tj] = *(const bf16x8*)(Bsh + (wc + tj * 16 + mrow) * 32 + quad * 8);
#pragma unroll
    for (int ti = 0; ti < 4; ++ti)
#pragma unroll
      for (int tj = 0; tj < 4; ++tj)
        acc[ti][tj] = __builtin_amdgcn_mfma_f32_16x16x32_bf16(
            af[ti], bfr[tj], acc[ti][tj], 0, 0, 0);
  }
  unsigned short* out = ws->wtt + (size_t)lin * 16384 + tid * 64;
#pragma unroll
  for (int ti = 0; ti < 4; ++ti)
#pragma unroll
    for (int tj = 0; tj < 4; ++tj) {
      ushort4 u;
      u.x = f2bf(acc[ti][tj][0]);
      u.y = f2bf(acc[ti][tj][1]);
      u.z = f2bf(acc[ti][tj][2]);
      u.w = f2bf(acc[ti][tj][3]);
      *(ushort4*)(out + (ti * 4 + tj) * 4) = u;
    }
}

// ---- epilogue helpers (forceinlined; KIND 0=SS, 1=ST) ----
template <int KIND, bool DIAG>
static __device__ __forceinline__ float epi_ss_st(
    const f32x4 (&acc)[4][4], const WS* __restrict__ ws,
    const unsigned short* Vsw, int p0, int q0, int wr, int wc, int mrow,
    int quad) {
  float cinv = ws->inv_d4;
  float k2 = 2.f * cinv;
  float cq[4], sdq[4];
  int lq[4];
#pragma unroll
  for (int tj = 0; tj < 4; ++tj) {
    int q = q0 + wc + tj * 16 + mrow;
    cq[tj] = -cinv * ws->sq[q];
    if (KIND == 0) {
      lq[tj] = ws->slab[q];
      sdq[tj] = ws->sdv[q];
    }
  }
  float local = 0.f;
#pragma unroll
  for (int ti = 0; ti < 4; ++ti) {
#pragma unroll
    for (int rg = 0; rg < 4; ++rg) {
      int p = p0 + wr + ti * 16 + quad * 4 + rg;
      float cpl = -cinv * ws->sq[p];
      int lp = ws->slab[p];
      float sp = ws->sdv[p];
#pragma unroll
      for (int tj = 0; tj < 4; ++tj) {
        float z = fminf(fmaf(k2, acc[ti][tj][rg], cpl + cq[tj]), 0.f);
        float y = __expf(z);
        float kv = y;
        y *= y; kv += y;
        y *= y; kv += y;
        y *= y; kv += y;
        y *= y; kv += y;
        float wv;
        if (KIND == 0) {
          wv = (lp == lq[tj]) ? sp * sdq[tj] : 0.f;
        } else {
          int ql = wc + tj * 16 + mrow;
          wv = sp * bf2f(Vsw[ql * 32 + ((lp + ql) & 31)]);
        }
        if (DIAG) {
          int q = q0 + wc + tj * 16 + mrow;
          float f = (q > p) ? 2.f : ((q == p) ? 1.f : 0.f);
          local = fmaf(wv * f, kv, local);
        } else {
          local = fmaf(wv, kv, local);
        }
      }
    }
  }
  if (!DIAG) local *= 2.f;
  return local;
}

template <bool DIAG>
static __device__ __forceinline__ float epi_tt(const f32x4 (&acc)[4][4],
                                               const WS* __restrict__ ws,
                                               const unsigned short* wttp,
                                               int p0, int q0, int wr, int wc,
                                               int mrow, int quad) {
  float cinv = ws->inv_d4;
  float k2 = 2.f * cinv;
  float cq[4];
#pragma unroll
  for (int tj = 0; tj < 4; ++tj)
    cq[tj] = -cinv * ws->sq[q0 + wc + tj * 16 + mrow];
  float cp[16];
#pragma unroll
  for (int ti = 0; ti < 4; ++ti)
#pragma unroll
    for (int rg = 0; rg < 4; ++rg)
      cp[ti * 4 + rg] = -cinv * ws->sq[p0 + wr + ti * 16 + quad * 4 + rg];
  float local = 0.f;
#pragma unroll
  for (int ti = 0; ti < 4; ++ti) {
#pragma unroll
    for (int tj = 0; tj < 4; ++tj) {
      ushort4 u = *(const ushort4*)(wttp + (ti * 4 + tj) * 4);
      float wf[4] = {bf2f(u.x), bf2f(u.y), bf2f(u.z), bf2f(u.w)};
#pragma unroll
      for (int rg = 0; rg < 4; ++rg) {
        float z = fminf(fmaf(k2, acc[ti][tj][rg], cp[ti * 4 + rg] + cq[tj]), 0.f);
        float y = __expf(z);
        float kv = y;
        y *= y; kv += y;
        y *= y; kv += y;
        y *= y; kv += y;
        y *= y; kv += y;
        if (DIAG) {
          int p = p0 + wr + ti * 16 + quad * 4 + rg;
          int q = q0 + wc + tj * 16 + mrow;
          float f = (q > p) ? 2.f : ((q == p) ? 1.f : 0.f);
          local = fmaf(wf[rg] * f, kv, local);
        } else {
          local = fmaf(wf[rg], kv, local);
        }
      }
    }
  }
  if (!DIAG) local *= 2.f;
  return local;
}

// Merged main kernel: all 2080 upper-tri 128x128 tile pairs.
// XCD-aware decode (round 6) + 32 KB LDS + swizzled fragment reads.
__global__ __launch_bounds__(256, 4) void k3_main(WS* __restrict__ ws) {
  int tid = threadIdx.x, w = tid >> 6, lane = tid & 63;
  int lin0 = blockIdx.x;
  int e = (lin0 & 7) * (NBLK / 8) + (lin0 >> 3);
  int b = 0, nb = 484, rem = e;
  while (rem >= nb) { rem -= nb; ++b; nb -= 64; }
  int base = b * 8;
  int bq_, r;
  if (rem < 36) {  // triangular head of the band (bq within band)
    bq_ = 0;
    while ((bq_ + 1) * (bq_ + 2) / 2 <= rem) ++bq_;
    r = rem - (bq_ * (bq_ + 1)) / 2;
  } else {  // full-height 8-row columns
    int t = rem - 36;
    bq_ = 8 + (t >> 3);
    r = t & 7;
  }
  int bp = base + r, bq = base + bq_;
  int p0 = bp * 128, q0 = bq * 128;

  __shared__ __align__(16) unsigned short Ash[2 * 128 * 32];  // 16 KB
  __shared__ __align__(16) unsigned short Bsh[2 * 128 * 32];  // 16 KB
  unsigned short* Vsw = Ash;   // aliased: ST V tile (8 KB), written post-barrier
  double* red = (double*)Bsh;  // aliased: block reduction scratch

  const int wr = (w >> 1) * 64, wc = (w & 1) * 64;
  const int mrow = lane & 15, quad = lane >> 4;
  f32x4 acc[4][4];
#pragma unroll
  for (int i = 0; i < 4; ++i)
#pragma unroll
    for (int j = 0; j < 4; ++j) acc[i][j] = (f32x4){0.f, 0.f, 0.f, 0.f};

  const unsigned short* Thi = ws->Thi;
  int rA = tid >> 2, cp8 = (tid & 3) * 8;
  unsigned short* ldsA = Ash + w * 512;
  unsigned short* ldsB = Bsh + w * 512;

  for (int s = 0; s < 4; ++s) {
    int ks = s * 64;
    __syncthreads();
#pragma unroll
    for (int c = 0; c < 2; ++c) {
      const unsigned short* gA = Thi + (size_t)(p0 + rA) * D + ks + c * 32 + cp8;
      GLD16(gA, ldsA + c * 4096);
      GLD16(gA + (size_t)64 * D, ldsA + c * 4096 + 2048);
      const unsigned short* gB = Thi + (size_t)(q0 + rA) * D + ks + c * 32 + cp8;
      GLD16(gB, ldsB + c * 4096);
      GLD16(gB + (size_t)64 * D, ldsB + c * 4096 + 2048);
    }
    __syncthreads();
#pragma unroll
    for (int c = 0; c < 2; ++c) {
      bf16x8 af[4], bfr[4];
#pragma unroll
      for (int ti = 0; ti < 4; ++ti) {
        int R = wr + ti * 16 + mrow;
        int slot = (quad + (R >> 1)) & 3;  // undo the global-side quad rotation
        af[ti] = *(const bf16x8*)(Ash + c * 4096 + R * 32 + slot * 8);
      }
#pragma unroll
      for (int tj = 0; tj < 4; ++tj) {
        int R = wc + tj * 16 + mrow;
        int slot = (quad + (R >> 1)) & 3;
        bfr[tj] = *(const bf16x8*)(Bsh + c * 4096 + R * 32 + slot * 8);
      }
#pragma unroll
      for (int ti = 0; ti < 4; ++ti)
#pragma unroll
        for (int tj = 0; tj < 4; ++tj)
          acc[ti][tj] = __builtin_amdgcn_mfma_f32_16x16x32_bf16(
              af[ti], bfr[tj], acc[ti][tj], 0, 0, 0);
    }
  }

  bool is_ss = (bq < 32);
  bool is_tt = (bp >= 32);
  __syncthreads();  // all feature-loop LDS reads done before Vsw overwrite
  if (!is_ss && !is_tt) {
    // ST: stage rotate-swizzled bf16 v rows of the q (target) tile into Ash.
    int rr = tid >> 1, h = (tid & 1) * 16;
    const float* vrow = ws->v + (size_t)(q0 + rr) * 32 + h;
#pragma unroll
    for (int j = 0; j < 16; ++j)
      Vsw[rr * 32 + ((h + j + rr) & 31)] = f2bf(vrow[j]);
  }
  __syncthreads();  // Vsw staged

  float local;
  if (is_ss) {
    if (bp == bq)
      local = epi_ss_st<0, true>(acc, ws, Vsw, p0, q0, wr, wc, mrow, quad);
    else
      local = epi_ss_st<0, false>(acc, ws, Vsw, p0, q0, wr, wc, mrow, quad);
  } else if (!is_tt) {
    local = epi_ss_st<1, false>(acc, ws, Vsw, p0, q0, wr, wc, mrow, quad);
  } else {
    int tp = bp - 32, tq = bq - 32;
    int ttlin = 32 * tp - (tp * (tp - 1)) / 2 + (tq - tp);
    const unsigned short* wttp = ws->wtt + (size_t)ttlin * 16384 + tid * 64;
    if (bp == bq)
      local = epi_tt<true>(acc, ws, wttp, p0, q0, wr, wc, mrow, quad);
    else
      local = epi_tt<false>(acc, ws, wttp, p0, q0, wr, wc, mrow, quad);
  }

  double dl = (double)local;
#pragma unroll
  for (int off = 32; off; off >>= 1) dl += __shfl_down(dl, off, 64);
  if (lane == 0) red[w] = dl;  // Bsh alias: all Bsh reads were pre-barrier
  __syncthreads();
  if (tid == 0) atomicAdd(&ws->acc_loss, red[0] + red[1] + red[2] + red[3]);
}

__global__ void k4_out(WS* __restrict__ ws, float* __restrict__ out) {
  out[0] = (float)(ws->acc_loss * (double)ws->inv_n_idx);
}

extern "C" void kernel_launch(void* const* d_in, const int* in_sizes, int n_in,
                              void* d_out, int out_size, void* d_ws, size_t ws_size,
                              hipStream_t stream) {
  const float* src = (const float*)d_in[0];
  const float* tgt = (const float*)d_in[1];
  const int* s_label = (const int*)d_in[2];
  const float* t_label = (const float*)d_in[3];
  float* out = (float*)d_out;
  WS* ws = (WS*)d_ws;  // ~23.2 MB

  k0_init<<<1, 64, 0, stream>>>(ws);
  kA1_stats<<<16, 256, 0, stream>>>(s_label, t_label, ws);
  kA2_final<<<1, 64, 0, stream>>>(ws);
  kB_prep<<<256, 256, 0, stream>>>(src, tgt, s_label, t_label, ws);
  kC_bw<<<1, 256, 0, stream>>>(ws);
  kW_tt<<<NTT, 256, 0, stream>>>(ws);
  k3_main<<<NBLK, 256, 0, stream>>>(ws);
  k4_out<<<1, 1, 0, stream>>>(ws, out);
}

// Round 8
// 178.240 us; speedup vs baseline: 1.0296x; 1.0296x over previous
//
#include <hip/hip_runtime.h>

// LMMD loss, round 8 = round 7 + (a) chunk-level double-buffered GLD16 pipeline
// in k3_main (overlap staging-drain with compute) + (b) Mpart pass removed
// (kB_prep double-atomic column sums; kC_bw is one wave).
// loss = (1/n_idx) * sum_{p<=q} f_pq * w_pq * K(p,q),  f=2 off-diag, 1 diag
//   v_i = s_vec[i] (i<B), v_{B+j} = -t_vec[j]
//   K = sum_t y^(2^t), y = exp(-relu(l2)/d4), d4 = largest denom
// Features: bf16 MFMA (hi-only; exact-match verified rounds 2-7).
// Weights: SS lookup (exact) / ST LDS gather (bf16) / TT precomputed bf16 tiles.
// Thi swizzle (round 7): quad q of row p stored at slot (q + (p>>1)) & 3;
// fragment reads use slot (quad + (R>>1)) & 3 -> 2-way (free) LDS banking.

#define B 4096
#define D 256
#define C 31
#define N2 8192
#define NTILE 64                       // 128-row tiles over 2B rows
#define NBLK (NTILE * (NTILE + 1) / 2) // 2080
#define NTT (32 * 33 / 2)              // 528 TT tile pairs

typedef __attribute__((ext_vector_type(8))) short bf16x8;
typedef __attribute__((ext_vector_type(4))) float f32x4;

struct WS {
  double acc_loss;
  double sum_sq;
  double Msum[256];  // column sums of total (double atomics)
  int s_cnt[32];
  float t_cnt[32];
  int t_pres[32];
  float s_div[32], t_div[32];
  float inv_n_idx;
  float inv_d4;
  float sq[N2];
  int slab[N2];
  float sdv[N2];
  alignas(16) unsigned short Thi[(size_t)N2 * D];   // bf16 features (swizzled)
  alignas(16) unsigned short vhi[(size_t)N2 * 32];  // bf16 v rows (linear)
  alignas(16) float v[(size_t)N2 * 32];             // exact f32 v rows
  alignas(16) unsigned short wtt[(size_t)NTT * 16384];  // bf16 TT weight tiles
};

static __device__ __forceinline__ unsigned short f2bf(float f) {
  unsigned int u = __float_as_uint(f);
  return (unsigned short)((u + 0x7fffu + ((u >> 16) & 1u)) >> 16);  // RNE
}
static __device__ __forceinline__ float bf2f(unsigned short s) {
  return __uint_as_float(((unsigned int)s) << 16);
}

#define GLD16(gsrc, ldst)                                                     \
  __builtin_amdgcn_global_load_lds(                                           \
      (const __attribute__((address_space(1))) void*)(gsrc),                  \
      (__attribute__((address_space(3))) void*)(ldst), 16, 0, 0)

__global__ void k0_init(WS* __restrict__ ws) {
  int tid = threadIdx.x;  // 256
  if (tid == 0) { ws->acc_loss = 0.0; ws->sum_sq = 0.0; }
  if (tid < 32) {
    ws->s_cnt[tid] = 0;
    ws->t_cnt[tid] = 0.f;
    ws->t_pres[tid] = 0;
  }
  ws->Msum[tid] = 0.0;
}

__global__ void kA1_stats(const int* __restrict__ s_label,
                          const float* __restrict__ t_label,
                          WS* __restrict__ ws) {
  __shared__ int ls[32];
  __shared__ float lt[32];
  __shared__ int lpres[32];
  int tid = threadIdx.x, lane = tid & 63;  // 256, 16 blocks
  if (tid < 32) { ls[tid] = 0; lt[tid] = 0.f; lpres[tid] = 0; }
  __syncthreads();
  int row = blockIdx.x * 256 + tid;
  atomicAdd(&ls[s_label[row]], 1);
  const float* r = t_label + (size_t)row * C;
  float best = -1e30f;
  int barg = 0;
#pragma unroll
  for (int c = 0; c < C; ++c) {
    float x = r[c];
    if (x > best) { best = x; barg = c; }  // first-max == jnp.argmax
    float s = x;
#pragma unroll
    for (int off = 32; off; off >>= 1) s += __shfl_down(s, off, 64);
    if (lane == 0) atomicAdd(&lt[c], s);
  }
  lpres[barg] = 1;  // benign race
  __syncthreads();
  if (tid < 32) {
    if (ls[tid]) atomicAdd(&ws->s_cnt[tid], ls[tid]);
    atomicAdd(&ws->t_cnt[tid], lt[tid]);
    if (lpres[tid]) ws->t_pres[tid] = 1;
  }
}

__global__ void kA2_final(WS* __restrict__ ws) {
  int tid = threadIdx.x;  // 64
  int m = 0;
  if (tid < 32) {
    int cnt = ws->s_cnt[tid];
    m = (tid < C) && (cnt > 0) && (ws->t_pres[tid] != 0);
    ws->s_div[tid] = m ? 1.f / (float)cnt : 0.f;
    float t = ws->t_cnt[tid];
    float ta = (t == 0.f) ? 100.f : t;
    ws->t_div[tid] = m ? 1.f / ta : 0.f;
  }
  unsigned long long bal = __ballot(m);
  if (tid == 0) ws->inv_n_idx = 1.f / fmaxf((float)__popcll(bal), 1.f);
}

__global__ __launch_bounds__(256) void kB_prep(const float* __restrict__ src,
                                               const float* __restrict__ tgt,
                                               const int* __restrict__ s_label,
                                               const float* __restrict__ t_label,
                                               WS* __restrict__ ws) {
  int tid = threadIdx.x, w = tid >> 6, lane = tid & 63;
  int r0 = blockIdx.x * 32;
  __shared__ float rsq[32];
  __shared__ float colp[4][256];
  float ca0 = 0.f, ca1 = 0.f, ca2 = 0.f, ca3 = 0.f;
  int ck = lane >> 3, qd = (lane >> 1) & 3, hf = lane & 1;
#pragma unroll
  for (int i = 0; i < 8; ++i) {
    int rr = w * 8 + i;
    int p = r0 + rr;
    const float* rp = (p < B) ? src + (size_t)p * D : tgt + (size_t)(p - B) * D;
    float4 x = *(const float4*)(rp + lane * 4);
    ushort4 hv;
    hv.x = f2bf(x.x); hv.y = f2bf(x.y); hv.z = f2bf(x.z); hv.w = f2bf(x.w);
    int slot = (qd + (p >> 1)) & 3;  // quad rotation within the 64-B chunk
    *(ushort4*)(&ws->Thi[(size_t)p * D + ck * 32 + slot * 8 + hf * 4]) = hv;
    ca0 += x.x; ca1 += x.y; ca2 += x.z; ca3 += x.w;
    float s = x.x * x.x + x.y * x.y + x.z * x.z + x.w * x.w;
#pragma unroll
    for (int off = 32; off; off >>= 1) s += __shfl_down(s, off, 64);
    if (lane == 0) rsq[rr] = s;
  }
  colp[w][lane * 4 + 0] = ca0;
  colp[w][lane * 4 + 1] = ca1;
  colp[w][lane * 4 + 2] = ca2;
  colp[w][lane * 4 + 3] = ca3;
  __syncthreads();
  if (tid < 32) {
    int p = r0 + tid;
    ws->sq[p] = rsq[tid];
    if (p < B) {
      int lb = s_label[p];
      ws->slab[p] = lb;
      ws->sdv[p] = ws->s_div[lb];
    } else {
      ws->slab[p] = 0;
      ws->sdv[p] = 0.f;
    }
  }
  // sum of this block's 32 sq values: wave 0, all 64 lanes active (no
  // divergent shuffles), lanes 32..63 contribute 0.
  if (tid < 64) {
    float ss = (tid < 32) ? rsq[tid] : 0.f;
#pragma unroll
    for (int off = 32; off; off >>= 1) ss += __shfl_down(ss, off, 64);
    if (tid == 0) atomicAdd(&ws->sum_sq, (double)ss);
  }
  // column sums -> 256 double atomics per block
  atomicAdd(&ws->Msum[tid],
            (double)(colp[0][tid] + colp[1][tid] + colp[2][tid] + colp[3][tid]));
  int vr = tid >> 3, cb = (tid & 7) * 4;
  int p = r0 + vr;
  float vals[4];
#pragma unroll
  for (int j = 0; j < 4; ++j) {
    int c = cb + j;
    float val = 0.f;
    if (c < C) {
      if (p < B)
        val = (s_label[p] == c) ? ws->s_div[c] : 0.f;
      else
        val = -t_label[(size_t)(p - B) * C + c] * ws->t_div[c];
    }
    vals[j] = val;
  }
  float4 vf; vf.x = vals[0]; vf.y = vals[1]; vf.z = vals[2]; vf.w = vals[3];
  *(float4*)(&ws->v[(size_t)p * 32 + cb]) = vf;
  ushort4 vh;
  vh.x = f2bf(vals[0]); vh.y = f2bf(vals[1]);
  vh.z = f2bf(vals[2]); vh.w = f2bf(vals[3]);
  *(ushort4*)(&ws->vhi[(size_t)p * 32 + cb]) = vh;
}

// One wave: inv_d4 from sum_sq and Msum.
__global__ void kC_bw(WS* __restrict__ ws) {
  int lane = threadIdx.x;  // 64
  double msq = 0.0;
#pragma unroll
  for (int i = 0; i < 4; ++i) {
    double m = ws->Msum[i * 64 + lane];
    msq += m * m;
  }
#pragma unroll
  for (int off = 32; off; off >>= 1) msq += __shfl_down(msq, off, 64);
  if (lane == 0) {
    double S = ws->sum_sq;
    double n = (double)N2;
    double sum_l2 = 2.0 * n * S - 2.0 * msq;
    double bw = sum_l2 / (n * n - n);
    bw = fmax(bw, 1e-6) * 0.25;          // / KERNEL_MUL^2
    double dc4 = fmax(bw * 16.0, 1e-6);  // largest denom
    ws->inv_d4 = (float)(1.0 / dc4);
  }
}

// Precompute TT weight tiles (bf16, stored in C-fragment order). vhi is linear.
__global__ __launch_bounds__(256, 2) void kW_tt(WS* __restrict__ ws) {
  int tid = threadIdx.x, w = tid >> 6, lane = tid & 63;
  int lin = blockIdx.x;
  int tp = 0;
  while (32 * (tp + 1) - ((tp + 1) * tp) / 2 <= lin) ++tp;
  int tq = tp + (lin - (32 * tp - (tp * (tp - 1)) / 2));
  int p0 = B + tp * 128, q0 = B + tq * 128;

  __shared__ __align__(16) unsigned short Ash[128 * 32];
  __shared__ __align__(16) unsigned short Bsh[128 * 32];
  const int wr = (w >> 1) * 64, wc = (w & 1) * 64;
  const int mrow = lane & 15, quad = lane >> 4;
  f32x4 acc[4][4];
#pragma unroll
  for (int i = 0; i < 4; ++i)
#pragma unroll
    for (int j = 0; j < 4; ++j) acc[i][j] = (f32x4){0.f, 0.f, 0.f, 0.f};

  int rA = tid >> 2, cp8 = (tid & 3) * 8;
  unsigned short* ldsA = Ash + w * 512;
  unsigned short* ldsB = Bsh + w * 512;
  const unsigned short* gA = ws->vhi + (size_t)(p0 + rA) * 32 + cp8;
  const unsigned short* gB = ws->vhi + (size_t)(q0 + rA) * 32 + cp8;
  GLD16(gA, ldsA);
  GLD16(gA + (size_t)64 * 32, ldsA + 2048);
  GLD16(gB, ldsB);
  GLD16(gB + (size_t)64 * 32, ldsB + 2048);
  __syncthreads();
  {
    bf16x8 af[4], bfr[4];
#pragma unroll
    for (int ti = 0; ti < 4; ++ti)
      af[ti] = *(const bf16x8*)(Ash + (wr + ti * 16 + mrow) * 32 + quad * 8);
#pragma unroll
    for (int tj = 0; tj < 4; ++tj)
      bfr[tj] = *(const bf16x8*)(Bsh + (wc + tj * 16 + mrow) * 32 + quad * 8);
#pragma unroll
    for (int ti = 0; ti < 4; ++ti)
#pragma unroll
      for (int tj = 0; tj < 4; ++tj)
        acc[ti][tj] = __builtin_amdgcn_mfma_f32_16x16x32_bf16(
            af[ti], bfr[tj], acc[ti][tj], 0, 0, 0);
  }
  unsigned short* out = ws->wtt + (size_t)lin * 16384 + tid * 64;
#pragma unroll
  for (int ti = 0; ti < 4; ++ti)
#pragma unroll
    for (int tj = 0; tj < 4; ++tj) {
      ushort4 u;
      u.x = f2bf(acc[ti][tj][0]);
      u.y = f2bf(acc[ti][tj][1]);
      u.z = f2bf(acc[ti][tj][2]);
      u.w = f2bf(acc[ti][tj][3]);
      *(ushort4*)(out + (ti * 4 + tj) * 4) = u;
    }
}

// ---- epilogue helpers (forceinlined; KIND 0=SS, 1=ST) ----
template <int KIND, bool DIAG>
static __device__ __forceinline__ float epi_ss_st(
    const f32x4 (&acc)[4][4], const WS* __restrict__ ws,
    const unsigned short* Vsw, int p0, int q0, int wr, int wc, int mrow,
    int quad) {
  float cinv = ws->inv_d4;
  float k2 = 2.f * cinv;
  float cq[4], sdq[4];
  int lq[4];
#pragma unroll
  for (int tj = 0; tj < 4; ++tj) {
    int q = q0 + wc + tj * 16 + mrow;
    cq[tj] = -cinv * ws->sq[q];
    if (KIND == 0) {
      lq[tj] = ws->slab[q];
      sdq[tj] = ws->sdv[q];
    }
  }
  float local = 0.f;
#pragma unroll
  for (int ti = 0; ti < 4; ++ti) {
#pragma unroll
    for (int rg = 0; rg < 4; ++rg) {
      int p = p0 + wr + ti * 16 + quad * 4 + rg;
      float cpl = -cinv * ws->sq[p];
      int lp = ws->slab[p];
      float sp = ws->sdv[p];
#pragma unroll
      for (int tj = 0; tj < 4; ++tj) {
        float z = fminf(fmaf(k2, acc[ti][tj][rg], cpl + cq[tj]), 0.f);
        float y = __expf(z);
        float kv = y;
        y *= y; kv += y;
        y *= y; kv += y;
        y *= y; kv += y;
        y *= y; kv += y;
        float wv;
        if (KIND == 0) {
          wv = (lp == lq[tj]) ? sp * sdq[tj] : 0.f;
        } else {
          int ql = wc + tj * 16 + mrow;
          wv = sp * bf2f(Vsw[ql * 32 + ((lp + ql) & 31)]);
        }
        if (DIAG) {
          int q = q0 + wc + tj * 16 + mrow;
          float f = (q > p) ? 2.f : ((q == p) ? 1.f : 0.f);
          local = fmaf(wv * f, kv, local);
        } else {
          local = fmaf(wv, kv, local);
        }
      }
    }
  }
  if (!DIAG) local *= 2.f;
  return local;
}

template <bool DIAG>
static __device__ __forceinline__ float epi_tt(const f32x4 (&acc)[4][4],
                                               const WS* __restrict__ ws,
                                               const unsigned short* wttp,
                                               int p0, int q0, int wr, int wc,
                                               int mrow, int quad) {
  float cinv = ws->inv_d4;
  float k2 = 2.f * cinv;
  float cq[4];
#pragma unroll
  for (int tj = 0; tj < 4; ++tj)
    cq[tj] = -cinv * ws->sq[q0 + wc + tj * 16 + mrow];
  float cp[16];
#pragma unroll
  for (int ti = 0; ti < 4; ++ti)
#pragma unroll
    for (int rg = 0; rg < 4; ++rg)
      cp[ti * 4 + rg] = -cinv * ws->sq[p0 + wr + ti * 16 + quad * 4 + rg];
  float local = 0.f;
#pragma unroll
  for (int ti = 0; ti < 4; ++ti) {
#pragma unroll
    for (int tj = 0; tj < 4; ++tj) {
      ushort4 u = *(const ushort4*)(wttp + (ti * 4 + tj) * 4);
      float wf[4] = {bf2f(u.x), bf2f(u.y), bf2f(u.z), bf2f(u.w)};
#pragma unroll
      for (int rg = 0; rg < 4; ++rg) {
        float z = fminf(fmaf(k2, acc[ti][tj][rg], cp[ti * 4 + rg] + cq[tj]), 0.f);
        float y = __expf(z);
        float kv = y;
        y *= y; kv += y;
        y *= y; kv += y;
        y *= y; kv += y;
        y *= y; kv += y;
        if (DIAG) {
          int p = p0 + wr + ti * 16 + quad * 4 + rg;
          int q = q0 + wc + tj * 16 + mrow;
          float f = (q > p) ? 2.f : ((q == p) ? 1.f : 0.f);
          local = fmaf(wf[rg] * f, kv, local);
        } else {
          local = fmaf(wf[rg], kv, local);
        }
      }
    }
  }
  if (!DIAG) local *= 2.f;
  return local;
}

// Merged main kernel, chunk-level double-buffered staging pipeline.
__global__ __launch_bounds__(256, 4) void k3_main(WS* __restrict__ ws) {
  int tid = threadIdx.x, w = tid >> 6, lane = tid & 63;
  int lin0 = blockIdx.x;
  int e = (lin0 & 7) * (NBLK / 8) + (lin0 >> 3);
  int b = 0, nb = 484, rem = e;
  while (rem >= nb) { rem -= nb; ++b; nb -= 64; }
  int base = b * 8;
  int bq_, r;
  if (rem < 36) {  // triangular head of the band (bq within band)
    bq_ = 0;
    while ((bq_ + 1) * (bq_ + 2) / 2 <= rem) ++bq_;
    r = rem - (bq_ * (bq_ + 1)) / 2;
  } else {  // full-height 8-row columns
    int t = rem - 36;
    bq_ = 8 + (t >> 3);
    r = t & 7;
  }
  int bp = base + r, bq = base + bq_;
  int p0 = bp * 128, q0 = bq * 128;

  __shared__ __align__(16) unsigned short Ash[2 * 128 * 32];  // 2 x 8 KB A bufs
  __shared__ __align__(16) unsigned short Bsh[2 * 128 * 32];  // 2 x 8 KB B bufs
  unsigned short* Vsw = Ash;   // aliased: ST V tile (8 KB), written post-barrier
  double* red = (double*)Bsh;  // aliased: block reduction scratch

  const int wr = (w >> 1) * 64, wc = (w & 1) * 64;
  const int mrow = lane & 15, quad = lane >> 4;
  f32x4 acc[4][4];
#pragma unroll
  for (int i = 0; i < 4; ++i)
#pragma unroll
    for (int j = 0; j < 4; ++j) acc[i][j] = (f32x4){0.f, 0.f, 0.f, 0.f};

  const unsigned short* Thi = ws->Thi;
  int rA = tid >> 2, cp8 = (tid & 3) * 8;
  const unsigned short* gA0 = Thi + (size_t)(p0 + rA) * D + cp8;
  const unsigned short* gB0 = Thi + (size_t)(q0 + rA) * D + cp8;

  // prologue: stage chunk 0 into buffer 0
  {
    unsigned short* la = Ash + w * 512;
    unsigned short* lb = Bsh + w * 512;
    GLD16(gA0, la);
    GLD16(gA0 + (size_t)64 * D, la + 2048);
    GLD16(gB0, lb);
    GLD16(gB0 + (size_t)64 * D, lb + 2048);
  }
  __syncthreads();  // drain chunk 0 (only fully-exposed drain)

#pragma unroll
  for (int c = 0; c < 8; ++c) {
    const int cur = (c & 1) * 4096;
    // stage chunk c+1 into the other buffer; its drain happens at this
    // iteration's end barrier, overlapped with the compute below.
    if (c < 7) {
      const int nxt = ((c + 1) & 1) * 4096;
      unsigned short* la = Ash + nxt + w * 512;
      unsigned short* lb = Bsh + nxt + w * 512;
      const unsigned short* ga = gA0 + (c + 1) * 32;
      const unsigned short* gb = gB0 + (c + 1) * 32;
      GLD16(ga, la);
      GLD16(ga + (size_t)64 * D, la + 2048);
      GLD16(gb, lb);
      GLD16(gb + (size_t)64 * D, lb + 2048);
    }
    // compute chunk c from the current buffer
    bf16x8 af[4], bfr[4];
#pragma unroll
    for (int ti = 0; ti < 4; ++ti) {
      int R = wr + ti * 16 + mrow;
      int slot = (quad + (R >> 1)) & 3;  // undo global-side quad rotation
      af[ti] = *(const bf16x8*)(Ash + cur + R * 32 + slot * 8);
    }
#pragma unroll
    for (int tj = 0; tj < 4; ++tj) {
      int R = wc + tj * 16 + mrow;
      int slot = (quad + (R >> 1)) & 3;
      bfr[tj] = *(const bf16x8*)(Bsh + cur + R * 32 + slot * 8);
    }
#pragma unroll
    for (int ti = 0; ti < 4; ++ti)
#pragma unroll
      for (int tj = 0; tj < 4; ++tj)
        acc[ti][tj] = __builtin_amdgcn_mfma_f32_16x16x32_bf16(
            af[ti], bfr[tj], acc[ti][tj], 0, 0, 0);
    __syncthreads();  // guards buffer reuse + drains chunk c+1 (overlapped)
  }

  bool is_ss = (bq < 32);
  bool is_tt = (bp >= 32);
  if (!is_ss && !is_tt) {
    // ST: stage rotate-swizzled bf16 v rows of the q (target) tile into Ash.
    int rr = tid >> 1, h = (tid & 1) * 16;
    const float* vrow = ws->v + (size_t)(q0 + rr) * 32 + h;
#pragma unroll
    for (int j = 0; j < 16; ++j)
      Vsw[rr * 32 + ((h + j + rr) & 31)] = f2bf(vrow[j]);
  }
  __syncthreads();  // Vsw staged

  float local;
  if (is_ss) {
    if (bp == bq)
      local = epi_ss_st<0, true>(acc, ws, Vsw, p0, q0, wr, wc, mrow, quad);
    else
      local = epi_ss_st<0, false>(acc, ws, Vsw, p0, q0, wr, wc, mrow, quad);
  } else if (!is_tt) {
    local = epi_ss_st<1, false>(acc, ws, Vsw, p0, q0, wr, wc, mrow, quad);
  } else {
    int tp = bp - 32, tq = bq - 32;
    int ttlin = 32 * tp - (tp * (tp - 1)) / 2 + (tq - tp);
    const unsigned short* wttp = ws->wtt + (size_t)ttlin * 16384 + tid * 64;
    if (bp == bq)
      local = epi_tt<true>(acc, ws, wttp, p0, q0, wr, wc, mrow, quad);
    else
      local = epi_tt<false>(acc, ws, wttp, p0, q0, wr, wc, mrow, quad);
  }

  double dl = (double)local;
#pragma unroll
  for (int off = 32; off; off >>= 1) dl += __shfl_down(dl, off, 64);
  if (lane == 0) red[w] = dl;  // Bsh alias: all Bsh reads were pre-barrier
  __syncthreads();
  if (tid == 0) atomicAdd(&ws->acc_loss, red[0] + red[1] + red[2] + red[3]);
}

__global__ void k4_out(WS* __restrict__ ws, float* __restrict__ out) {
  out[0] = (float)(ws->acc_loss * (double)ws->inv_n_idx);
}

extern "C" void kernel_launch(void* const* d_in, const int* in_sizes, int n_in,
                              void* d_out, int out_size, void* d_ws, size_t ws_size,
                              hipStream_t stream) {
  const float* src = (const float*)d_in[0];
  const float* tgt = (const float*)d_in[1];
  const int* s_label = (const int*)d_in[2];
  const float* t_label = (const float*)d_in[3];
  float* out = (float*)d_out;
  WS* ws = (WS*)d_ws;  // ~23 MB

  k0_init<<<1, 256, 0, stream>>>(ws);
  kA1_stats<<<16, 256, 0, stream>>>(s_label, t_label, ws);
  kA2_final<<<1, 64, 0, stream>>>(ws);
  kB_prep<<<256, 256, 0, stream>>>(src, tgt, s_label, t_label, ws);
  kC_bw<<<1, 64, 0, stream>>>(ws);
  kW_tt<<<NTT, 256, 0, stream>>>(ws);
  k3_main<<<NBLK, 256, 0, stream>>>(ws);
  k4_out<<<1, 1, 0, stream>>>(ws, out);
}